// Round 1
// baseline (2197.900 us; speedup 1.0000x reference)
//
#include <hip/hip_runtime.h>
#include <math.h>

#define HID 128
#define EMB 64
#define NLAYERS 4

// cfg constants
#define CSE_C 0.5f
#define CLE_C 0.00574f
#define DCOEF (CSE_C - CLE_C)          // 0.49426
#define KCOEF (1.0f - CSE_C + CLE_C)   // 0.50574
#define AC1_C 2.0f
#define AC2_C 1.0f
#define AC3_C 0.01f

__device__ __forceinline__ float lane_bcast(float v, int srclane) {
    return __uint_as_float(__builtin_amdgcn_readlane(__float_as_uint(v), srclane));
}

// Second-order forward-mode jet propagation.
// Per branch (original / x0-mirrored input), 6 channels:
//   0: value, 1: d/dt, 2: d/dx0, 3: d2/dx0^2, 4: d/dx1, 5: d2/dx1^2
// Lane l owns hidden elements l (lo) and l+64 (hi).
extern "C" __global__ __launch_bounds__(512)
void pinn_ac_kernel(const float* __restrict__ x, const float* __restrict__ t,
                    const float* __restrict__ B, const float* __restrict__ Wh,
                    const float* __restrict__ bh, const float* __restrict__ Wout,
                    const float* __restrict__ bout, float* __restrict__ out, int npts)
{
    __shared__ float Wlds[HID * HID];   // 64 KB: current layer's weights

    const int tid  = threadIdx.x;
    const int lane = tid & 63;
    const int wave = tid >> 6;          // 0..7, one point per wave
    const int pt   = blockIdx.x * 8 + wave;
    const int ptc  = pt < npts ? pt : npts - 1;

    const float x0 = x[ptc * 2 + 0];
    const float x1 = x[ptc * 2 + 1];
    const float tt = t[ptc];

    // ---- Fourier feature layer: f_e = 2*pi*(z @ B), h = [sin f, cos f] ----
    const float TWO_PI = 6.28318530717958647692f;
    const float b0 = TWO_PI * B[0 * EMB + lane];   // df/dx0
    const float b1 = TWO_PI * B[1 * EMB + lane];   // df/dx1
    const float b2 = TWO_PI * B[2 * EMB + lane];   // df/dt

    float h_lo[12], h_hi[12];
    #pragma unroll
    for (int br = 0; br < 2; ++br) {
        const float zx0 = br ? -x0 : x0;
        const float fv = zx0 * b0 + x1 * b1 + tt * b2;
        float sf, cf;
        sincosf(fv, &sf, &cf);
        const int c0 = br * 6;
        // sin part (element index = lane)
        h_lo[c0 + 0] = sf;
        h_lo[c0 + 1] = cf * b2;
        h_lo[c0 + 2] = cf * b0;
        h_lo[c0 + 3] = -sf * b0 * b0;   // f''=0, so sigma'' * (f')^2
        h_lo[c0 + 4] = cf * b1;
        h_lo[c0 + 5] = -sf * b1 * b1;
        // cos part (element index = lane + 64)
        h_hi[c0 + 0] = cf;
        h_hi[c0 + 1] = -sf * b2;
        h_hi[c0 + 2] = -sf * b0;
        h_hi[c0 + 3] = -cf * b0 * b0;
        h_hi[c0 + 4] = -sf * b1;
        h_hi[c0 + 5] = -cf * b1 * b1;
    }

    // ---- hidden layers: h = tanh(h @ W + b), jets propagated ----
    for (int L = 0; L < NLAYERS; ++L) {
        __syncthreads();
        {   // cooperative stage of Wh[L] (128x128 f32, row-major) into LDS
            const float4* src = (const float4*)(Wh + (size_t)L * HID * HID);
            float4* dst = (float4*)Wlds;
            #pragma unroll
            for (int k = 0; k < 8; ++k) dst[tid + k * 512] = src[tid + k * 512];
        }
        __syncthreads();

        float acc_lo[12], acc_hi[12];
        #pragma unroll
        for (int c = 0; c < 12; ++c) { acc_lo[c] = 0.f; acc_hi[c] = 0.f; }

        // rows 0..63 come from h_lo (element i lives in lane i)
        #pragma unroll 8
        for (int i = 0; i < 64; ++i) {
            const float w0 = Wlds[i * HID + lane];
            const float w1 = Wlds[i * HID + 64 + lane];
            #pragma unroll
            for (int c = 0; c < 12; ++c) {
                const float hb = lane_bcast(h_lo[c], i);
                acc_lo[c] = fmaf(hb, w0, acc_lo[c]);
                acc_hi[c] = fmaf(hb, w1, acc_hi[c]);
            }
        }
        // rows 64..127 come from h_hi (element 64+i lives in lane i)
        #pragma unroll 8
        for (int i = 0; i < 64; ++i) {
            const float w0 = Wlds[(64 + i) * HID + lane];
            const float w1 = Wlds[(64 + i) * HID + 64 + lane];
            #pragma unroll
            for (int c = 0; c < 12; ++c) {
                const float hb = lane_bcast(h_hi[c], i);
                acc_lo[c] = fmaf(hb, w0, acc_lo[c]);
                acc_hi[c] = fmaf(hb, w1, acc_hi[c]);
            }
        }

        const float bv0 = bh[L * HID + lane];
        const float bv1 = bh[L * HID + 64 + lane];
        #pragma unroll
        for (int br = 0; br < 2; ++br) {
            const int c0 = br * 6;
            {
                const float a  = acc_lo[c0] + bv0;
                const float y  = tanhf(a);
                const float s  = 1.f - y * y;
                const float d1 = acc_lo[c0 + 2], d2 = acc_lo[c0 + 4];
                h_lo[c0 + 0] = y;
                h_lo[c0 + 1] = s * acc_lo[c0 + 1];
                h_lo[c0 + 2] = s * d1;
                h_lo[c0 + 3] = s * (acc_lo[c0 + 3] - 2.f * y * d1 * d1);
                h_lo[c0 + 4] = s * d2;
                h_lo[c0 + 5] = s * (acc_lo[c0 + 5] - 2.f * y * d2 * d2);
            }
            {
                const float a  = acc_hi[c0] + bv1;
                const float y  = tanhf(a);
                const float s  = 1.f - y * y;
                const float d1 = acc_hi[c0 + 2], d2 = acc_hi[c0 + 4];
                h_hi[c0 + 0] = y;
                h_hi[c0 + 1] = s * acc_hi[c0 + 1];
                h_hi[c0 + 2] = s * d1;
                h_hi[c0 + 3] = s * (acc_hi[c0 + 3] - 2.f * y * d1 * d1);
                h_hi[c0 + 4] = s * d2;
                h_hi[c0 + 5] = s * (acc_hi[c0 + 5] - 2.f * y * d2 * d2);
            }
        }
    }

    // ---- output layer: o_j = h @ Wout[:,j] + bout[j] ----
    // need all 6 channels of o0 and value of o1, per branch -> 14 reductions
    const float wo0_lo = Wout[lane * 2 + 0];
    const float wo1_lo = Wout[lane * 2 + 1];
    const float wo0_hi = Wout[(lane + 64) * 2 + 0];
    const float wo1_hi = Wout[(lane + 64) * 2 + 1];

    float red[14];
    #pragma unroll
    for (int br = 0; br < 2; ++br) {
        #pragma unroll
        for (int c = 0; c < 6; ++c)
            red[br * 7 + c] = h_lo[br * 6 + c] * wo0_lo + h_hi[br * 6 + c] * wo0_hi;
        red[br * 7 + 6] = h_lo[br * 6 + 0] * wo1_lo + h_hi[br * 6 + 0] * wo1_hi;
    }
    #pragma unroll
    for (int m = 1; m < 64; m <<= 1) {
        #pragma unroll
        for (int r = 0; r < 14; ++r)
            red[r] += __shfl_xor(red[r], m, 64);
    }

    // ---- hard constraint + symmetrized averages ----
    const float bo0 = bout[0], bo1 = bout[1];
    float phi = 0.f, cval = 0.f, phit = 0.f, lap = 0.f;
    #pragma unroll
    for (int br = 0; br < 2; ++br) {
        const float o0 = red[br * 7 + 0] + bo0;
        const float T  = tanhf(o0);
        const float p  = 0.5f * T + 0.5f;
        const float s  = 0.5f * (1.f - T * T);         // dp/do0
        const float p_t   = s * red[br * 7 + 1];
        const float d1    = red[br * 7 + 2];
        const float d2    = red[br * 7 + 4];
        const float p_xx0 = s * (red[br * 7 + 3] - 2.f * T * d1 * d1);
        const float p_xx1 = s * (red[br * 7 + 5] - 2.f * T * d2 * d2);
        const float o1 = red[br * 7 + 6] + bo1;
        const float cl = KCOEF * (0.5f * tanhf(o1) + 0.5f);
        const float cbr = DCOEF * ((-2.f * p + 3.f) * p * p) + cl;
        phi  += 0.5f * p;
        cval += 0.5f * cbr;
        phit += 0.5f * p_t;
        lap  += 0.5f * (p_xx0 + p_xx1);
    }

    // ---- Allen-Cahn residual ----
    const float h_phi = (-2.f * phi + 3.f) * phi * phi;
    const float dh    = 6.f * phi * (1.f - phi);                 // -6p^2+6p
    const float dg    = ((4.f * phi - 6.f) * phi + 2.f) * phi;   // 4p^3-6p^2+2p
    const float ac = phit
                   - AC1_C * ((cval - h_phi * DCOEF - CLE_C) * DCOEF) * dh
                   + AC2_C * dg
                   - AC3_C * lap;

    if (lane == 0 && pt < npts) out[pt] = ac;
}

extern "C" void kernel_launch(void* const* d_in, const int* in_sizes, int n_in,
                              void* d_out, int out_size, void* d_ws, size_t ws_size,
                              hipStream_t stream) {
    const float* x    = (const float*)d_in[0];
    const float* t    = (const float*)d_in[1];
    const float* B    = (const float*)d_in[2];
    const float* Wh   = (const float*)d_in[3];
    const float* bh   = (const float*)d_in[4];
    const float* Wout = (const float*)d_in[5];
    const float* bout = (const float*)d_in[6];
    float* out = (float*)d_out;

    const int npts = in_sizes[0] / 2;            // x is (N,2)
    const int nblocks = (npts + 7) / 8;          // 8 points (waves) per block
    hipLaunchKernelGGL(pinn_ac_kernel, dim3(nblocks), dim3(512), 0, stream,
                       x, t, B, Wh, bh, Wout, bout, out, npts);
}

// Round 2
// 235.996 us; speedup vs baseline: 9.3133x; 9.3133x over previous
//
#include <hip/hip_runtime.h>
#include <math.h>

#define PTS_PER_BLOCK 12
#define NPTS_PER_WAVE 3

typedef _Float16 h8 __attribute__((ext_vector_type(8)));
typedef float    f4 __attribute__((ext_vector_type(4)));
typedef unsigned int uint32;

// cfg constants
#define CSE_C 0.5f
#define CLE_C 0.00574f
#define DCOEF (CSE_C - CLE_C)          // 0.49426
#define KCOEF (1.0f - CSE_C + CLE_C)   // 0.50574

__device__ __forceinline__ float tanh_fast(float xx) {
    // tanh(x) = 1 - 2/(e^{2x}+1); inf/0 limits give +-1 correctly
    float e = __expf(2.0f * xx);
    float r = __builtin_amdgcn_rcpf(e + 1.0f);
    return fmaf(-2.0f, r, 1.0f);
}
__device__ __forceinline__ unsigned short f2h(float a) {
    union { _Float16 h; unsigned short u; } ua; ua.h = (_Float16)a; return ua.u;
}
__device__ __forceinline__ uint32 pk2h(float a, float b) {
    return (uint32)f2h(a) | ((uint32)f2h(b) << 16);
}
__device__ __forceinline__ void upk2(uint32 u, float& a, float& b) {
    union { unsigned short u; _Float16 h; } xa, xb;
    xa.u = (unsigned short)(u & 0xffffu); a = (float)xa.h;
    xb.u = (unsigned short)(u >> 16);     b = (float)xb.h;
}

// ---------------------------------------------------------------------------
// Prep: Wh (4,128,128 f32) -> A-fragment-ordered f16 W^T tiles.
// A-frag (16x16x32 f16): lane holds row m=lane&15, k=(lane>>4)*8+e (contig 8).
// Value = W^T[m,k] = Wh[L][k_j][m_jout]. Dword layout:
//   Wp[ ((L*4+kt)*8+jo)*256 + lane*4 + d ] packs (j=kt*32+(lane>>4)*8+2d, j+1)
// ---------------------------------------------------------------------------
extern "C" __global__ __launch_bounds__(256)
void pinn_prep(const float* __restrict__ Wh, uint32* __restrict__ Wp)
{
    int gid  = blockIdx.x * 256 + threadIdx.x;       // 0..32767
    int d    = gid & 3;
    int lane = (gid >> 2) & 63;
    int jo   = (gid >> 8) & 7;
    int kt   = (gid >> 11) & 3;
    int L    = gid >> 13;
    int j    = kt * 32 + (lane >> 4) * 8 + 2 * d;
    int jout = jo * 16 + (lane & 15);
    float w0 = Wh[(L * 128 + j) * 128 + jout];
    float w1 = Wh[(L * 128 + j + 1) * 128 + jout];
    Wp[gid] = pk2h(w0, w1);
}

// ---------------------------------------------------------------------------
// Main: one wave = 3 points = 6 branch-points (bp), 5 jet channels each:
//   ch: 0=value 1=d/dt 2=d/dx0 3=d/dx1 4=laplacian''
// Per wave, 32 MFMA columns = 2 col-tiles x (3 bp x 5ch + 1 pad).
// H lives in per-wave LDS rows [32][136] f16 (stride 272B: conflict-free
// b128 reads, 2-way-free b32 phase-B column access).
// ---------------------------------------------------------------------------
extern "C" __global__ __launch_bounds__(256, 2)
void pinn_mfma(const float* __restrict__ x, const float* __restrict__ t,
               const float* __restrict__ B, const uint32* __restrict__ Wp,
               const float* __restrict__ bh, const float* __restrict__ Wout,
               const float* __restrict__ bout, float* __restrict__ out, int npts)
{
    __shared__ __align__(16) uint32 Wlds[8192];              // 32 KB A-frags
    __shared__ __align__(16) unsigned short H[4][32][136];   // 34816 B

    const int tid  = threadIdx.x;
    const int lane = tid & 63;
    const int wv   = tid >> 6;
    const int c    = lane & 15;
    const int g    = lane >> 4;
    const int base_pt = blockIdx.x * PTS_PER_BLOCK + wv * NPTS_PER_WAVE;

    unsigned short* Hb = &H[wv][0][0];

    // ---------------- embedding (writes layer-0 H) ----------------
    {
        const float TWO_PI = 6.28318530717958647692f;
        float b0 = TWO_PI * B[lane];
        float b1 = TWO_PI * B[64 + lane];
        float b2 = TWO_PI * B[128 + lane];
        float bsq = fmaf(b0, b0, b1 * b1);
        #pragma unroll
        for (int b = 0; b < 6; ++b) {
            int pl = b >> 1, mir = b & 1;
            int pt = base_pt + pl; if (pt > npts - 1) pt = npts - 1;
            float x0 = x[2 * pt], x1 = x[2 * pt + 1], tt = t[pt];
            if (mir) x0 = -x0;
            float f = fmaf(x0, b0, fmaf(x1, b1, tt * b2));
            float sf, cf; __sincosf(f, &sf, &cf);
            int rs = (b < 3) ? 5 * b : 16 + 5 * (b - 3);
            // sin half (feature j = lane)
            Hb[(rs + 0) * 136 + lane] = f2h(sf);
            Hb[(rs + 1) * 136 + lane] = f2h(cf * b2);
            Hb[(rs + 2) * 136 + lane] = f2h(cf * b0);
            Hb[(rs + 3) * 136 + lane] = f2h(cf * b1);
            Hb[(rs + 4) * 136 + lane] = f2h(-sf * bsq);
            // cos half (feature j = lane + 64)
            Hb[(rs + 0) * 136 + 64 + lane] = f2h(cf);
            Hb[(rs + 1) * 136 + 64 + lane] = f2h(-sf * b2);
            Hb[(rs + 2) * 136 + 64 + lane] = f2h(-sf * b0);
            Hb[(rs + 3) * 136 + 64 + lane] = f2h(-sf * b1);
            Hb[(rs + 4) * 136 + 64 + lane] = f2h(-cf * bsq);
        }
    }

    // ---------------- hidden layers ----------------
    const int   isv = (c == 0) | (c == 5) | (c == 10) | (c == 15);
    const float vm  = isv ? 1.0f : 0.0f;

    for (int L = 0; L < 4; ++L) {
        __syncthreads();                       // Wlds reuse safe
        {   // stage layer's A-frags: 32 KB, 8 x dwordx4 per thread
            const uint4* gw = (const uint4*)(Wp + L * 8192);
            uint4 tmp[8];
            #pragma unroll
            for (int i = 0; i < 8; ++i) tmp[i] = gw[tid + i * 256];
            #pragma unroll
            for (int i = 0; i < 8; ++i) *(uint4*)&Wlds[(tid + i * 256) * 4] = tmp[i];
        }
        __syncthreads();

        // B-fragments: col = own ch-row, k = j (contiguous 8)
        h8 bf[2][4];
        #pragma unroll
        for (int ct = 0; ct < 2; ++ct)
            #pragma unroll
            for (int kt = 0; kt < 4; ++kt)
                bf[ct][kt] = *(const h8*)&Hb[(ct * 16 + c) * 136 + kt * 32 + g * 8];

        // acc init: bias only on value columns (derivative channels lose bias)
        f4 acc[2][8];
        #pragma unroll
        for (int jo = 0; jo < 8; ++jo) {
            f4 bv = *(const f4*)&bh[L * 128 + jo * 16 + g * 4];
            acc[0][jo] = bv * vm;
            acc[1][jo] = bv * vm;
        }
        // MFMA: 8 jo-tiles x 4 k-steps x 2 col-tiles
        #pragma unroll
        for (int jo = 0; jo < 8; ++jo) {
            #pragma unroll
            for (int kt = 0; kt < 4; ++kt) {
                h8 af = *(const h8*)&Wlds[(kt * 8 + jo) * 256 + lane * 4];
                acc[0][jo] = __builtin_amdgcn_mfma_f32_16x16x32_f16(af, bf[0][kt], acc[0][jo], 0, 0, 0);
                acc[1][jo] = __builtin_amdgcn_mfma_f32_16x16x32_f16(af, bf[1][kt], acc[1][jo], 0, 0, 0);
            }
        }

        // phase A: write raw pre-activations (C layout: row=jo*16+g*4+r, col=c)
        #pragma unroll
        for (int ct = 0; ct < 2; ++ct)
            #pragma unroll
            for (int jo = 0; jo < 8; ++jo) {
                uint2 w;
                w.x = pk2h(acc[ct][jo][0], acc[ct][jo][1]);
                w.y = pk2h(acc[ct][jo][2], acc[ct][jo][3]);
                *(uint2*)&Hb[(ct * 16 + c) * 136 + jo * 16 + g * 4] = w;
            }
        asm volatile("s_waitcnt lgkmcnt(0)" ::: "memory");

        // phase B: lane-private j-columns (j = 2*lane, 2*lane+1)
        {
            const int jb = 2 * lane;
            #pragma unroll
            for (int b = 0; b < 6; ++b) {
                int rs = (b < 3) ? 5 * b : 16 + 5 * (b - 3);
                uint32 uv = *(const uint32*)&Hb[(rs + 0) * 136 + jb];
                uint32 ut = *(const uint32*)&Hb[(rs + 1) * 136 + jb];
                uint32 u0 = *(const uint32*)&Hb[(rs + 2) * 136 + jb];
                uint32 u1 = *(const uint32*)&Hb[(rs + 3) * 136 + jb];
                uint32 uL = *(const uint32*)&Hb[(rs + 4) * 136 + jb];
                float v0, v1, t0, t1, p0, p1, q0, q1, L0, L1;
                upk2(uv, v0, v1); upk2(ut, t0, t1); upk2(u0, p0, p1);
                upk2(u1, q0, q1); upk2(uL, L0, L1);
                float y0 = tanh_fast(v0), y1 = tanh_fast(v1);
                float s0 = fmaf(-y0, y0, 1.f), s1 = fmaf(-y1, y1, 1.f);
                float qq0 = fmaf(p0, p0, q0 * q0), qq1 = fmaf(p1, p1, q1 * q1);
                *(uint32*)&Hb[(rs + 0) * 136 + jb] = pk2h(y0, y1);
                *(uint32*)&Hb[(rs + 1) * 136 + jb] = pk2h(s0 * t0, s1 * t1);
                *(uint32*)&Hb[(rs + 2) * 136 + jb] = pk2h(s0 * p0, s1 * p1);
                *(uint32*)&Hb[(rs + 3) * 136 + jb] = pk2h(s0 * q0, s1 * q1);
                *(uint32*)&Hb[(rs + 4) * 136 + jb] =
                    pk2h(s0 * fmaf(-2.f * y0, qq0, L0), s1 * fmaf(-2.f * y1, qq1, L1));
            }
        }
        asm volatile("s_waitcnt lgkmcnt(0)" ::: "memory");
    }

    // ---------------- output layer + residual ----------------
    {
        const int jb = 2 * lane;
        float w00 = Wout[jb * 2 + 0], w01 = Wout[jb * 2 + 1];
        float w10 = Wout[jb * 2 + 2], w11 = Wout[jb * 2 + 3];
        float red[36];
        #pragma unroll
        for (int b = 0; b < 6; ++b) {
            int rs = (b < 3) ? 5 * b : 16 + 5 * (b - 3);
            float v0, v1, t0, t1, p0, p1, q0, q1, L0, L1;
            upk2(*(const uint32*)&Hb[(rs + 0) * 136 + jb], v0, v1);
            upk2(*(const uint32*)&Hb[(rs + 1) * 136 + jb], t0, t1);
            upk2(*(const uint32*)&Hb[(rs + 2) * 136 + jb], p0, p1);
            upk2(*(const uint32*)&Hb[(rs + 3) * 136 + jb], q0, q1);
            upk2(*(const uint32*)&Hb[(rs + 4) * 136 + jb], L0, L1);
            red[b * 6 + 0] = fmaf(v0, w00, v1 * w10);
            red[b * 6 + 1] = fmaf(t0, w00, t1 * w10);
            red[b * 6 + 2] = fmaf(p0, w00, p1 * w10);
            red[b * 6 + 3] = fmaf(q0, w00, q1 * w10);
            red[b * 6 + 4] = fmaf(L0, w00, L1 * w10);
            red[b * 6 + 5] = fmaf(v0, w01, v1 * w11);
        }
        #pragma unroll
        for (int m = 1; m < 64; m <<= 1) {
            #pragma unroll
            for (int r = 0; r < 36; ++r)
                red[r] += __shfl_xor(red[r], m, 64);
        }

        if (lane < 3) {
            int pt = base_pt + lane;
            if (pt < npts) {
                float bo0 = bout[0], bo1 = bout[1];
                float ph = 0.f, cv = 0.f, ptd = 0.f, lp = 0.f;
                #pragma unroll
                for (int br = 0; br < 2; ++br) {
                    const float* rr = &red[(lane * 2 + br) * 6];
                    float T = tanh_fast(rr[0] + bo0);
                    float p = fmaf(0.5f, T, 0.5f);
                    float s = 0.5f * fmaf(-T, T, 1.f);
                    float d1 = rr[2], d2 = rr[3];
                    float lap = s * rr[4] - 2.f * T * s * fmaf(d1, d1, d2 * d2);
                    float cl = KCOEF * fmaf(0.5f, tanh_fast(rr[5] + bo1), 0.5f);
                    float cb = fmaf(DCOEF, (-2.f * p + 3.f) * p * p, cl);
                    ph  += 0.5f * p;
                    cv  += 0.5f * cb;
                    ptd += 0.5f * s * rr[1];
                    lp  += 0.5f * lap;
                }
                float hph = (-2.f * ph + 3.f) * ph * ph;
                float dh  = 6.f * ph * (1.f - ph);
                float dg  = ((4.f * ph - 6.f) * ph + 2.f) * ph;
                float ac  = ptd
                          - 2.f * ((cv - hph * DCOEF - CLE_C) * DCOEF) * dh
                          + dg
                          - 0.01f * lp;
                out[pt] = ac;
            }
        }
    }
}

extern "C" void kernel_launch(void* const* d_in, const int* in_sizes, int n_in,
                              void* d_out, int out_size, void* d_ws, size_t ws_size,
                              hipStream_t stream) {
    const float* x    = (const float*)d_in[0];
    const float* t    = (const float*)d_in[1];
    const float* B    = (const float*)d_in[2];
    const float* Wh   = (const float*)d_in[3];
    const float* bh   = (const float*)d_in[4];
    const float* Wout = (const float*)d_in[5];
    const float* bout = (const float*)d_in[6];
    float* out = (float*)d_out;
    uint32* Wp = (uint32*)d_ws;                       // 128 KB scratch

    const int npts = in_sizes[0] / 2;
    hipLaunchKernelGGL(pinn_prep, dim3(128), dim3(256), 0, stream, Wh, Wp);
    const int nb = (npts + PTS_PER_BLOCK - 1) / PTS_PER_BLOCK;
    hipLaunchKernelGGL(pinn_mfma, dim3(nb), dim3(256), 0, stream,
                       x, t, B, Wp, bh, Wout, bout, out, npts);
}

// Round 3
// 178.932 us; speedup vs baseline: 12.2834x; 1.3189x over previous
//
#include <hip/hip_runtime.h>
#include <math.h>

#define PTS_PER_BLOCK 12
#define NPTS_PER_WAVE 3

typedef _Float16 h8 __attribute__((ext_vector_type(8)));
typedef float    f4 __attribute__((ext_vector_type(4)));
typedef unsigned int uint32;

// cfg constants
#define CSE_C 0.5f
#define CLE_C 0.00574f
#define DCOEF (CSE_C - CLE_C)          // 0.49426
#define KCOEF (1.0f - CSE_C + CLE_C)   // 0.50574

__device__ __forceinline__ float tanh_fast(float xx) {
    float e = __expf(2.0f * xx);
    float r = __builtin_amdgcn_rcpf(e + 1.0f);
    return fmaf(-2.0f, r, 1.0f);
}
__device__ __forceinline__ unsigned short f2h(float a) {
    union { _Float16 h; unsigned short u; } ua; ua.h = (_Float16)a; return ua.u;
}
__device__ __forceinline__ uint32 pk2h(float a, float b) {
    return (uint32)f2h(a) | ((uint32)f2h(b) << 16);
}
__device__ __forceinline__ void upk2(uint32 u, float& a, float& b) {
    union { unsigned short u; _Float16 h; } xa, xb;
    xa.u = (unsigned short)(u & 0xffffu); a = (float)xa.h;
    xb.u = (unsigned short)(u >> 16);     b = (float)xb.h;
}
__device__ __forceinline__ h8 h8_from4(uint32 a, uint32 b, uint32 c, uint32 d) {
    union { uint32 u[4]; h8 v; } x; x.u[0] = a; x.u[1] = b; x.u[2] = c; x.u[3] = d;
    return x.v;
}

// ---------------------------------------------------------------------------
// Prep: Wh (4,128,128 f32) -> A-fragment-ordered f16 W^T tiles, [L][jo][kt]
// contiguous so the main kernel streams 4KB per jo-tile.
// A-frag (16x16x32 f16): lane holds row m=lane&15, k=(lane>>4)*8+e.
//   Wp[ ((L*8+jo)*4+kt)*256 + lane*4 + d ] packs (k=kt*32+(lane>>4)*8+2d, k+1)
// value = W^T[m,k] = Wh[L][k][jout=jo*16+m]
// ---------------------------------------------------------------------------
extern "C" __global__ __launch_bounds__(256)
void pinn_prep(const float* __restrict__ Wh, uint32* __restrict__ Wp)
{
    int gid  = blockIdx.x * 256 + threadIdx.x;       // 0..32767
    int d    = gid & 3;
    int lane = (gid >> 2) & 63;
    int kt   = (gid >> 8) & 3;
    int jo   = (gid >> 10) & 7;
    int L    = gid >> 13;
    int j    = kt * 32 + (lane >> 4) * 8 + 2 * d;
    int jout = jo * 16 + (lane & 15);
    float w0 = Wh[(L * 128 + j) * 128 + jout];
    float w1 = Wh[(L * 128 + j + 1) * 128 + jout];
    Wp[gid] = pk2h(w0, w1);
}

// ---------------------------------------------------------------------------
// Main: barrier-free. One wave = 3 points = 6 branch-points (bp), 5 channels:
//   ch: 0=value 1=d/dt 2=d/dx0 3=d/dx1 4=laplacian
// Per wave, 32 MFMA columns = 2 col-tiles x (3bp x 5ch + pad).
// H per wave in LDS [32][136] f16 (8704 B); W streamed from global (L2).
// ---------------------------------------------------------------------------
extern "C" __global__ __launch_bounds__(256, 4)
void pinn_mfma(const float* __restrict__ x, const float* __restrict__ t,
               const float* __restrict__ B, const uint32* __restrict__ Wp,
               const float* __restrict__ bh, const float* __restrict__ Wout,
               const float* __restrict__ bout, float* __restrict__ out, int npts)
{
    __shared__ __align__(16) unsigned short H[4][32][136];   // 34816 B

    const int tid  = threadIdx.x;
    const int lane = tid & 63;
    const int wv   = tid >> 6;
    const int c    = lane & 15;
    const int g    = lane >> 4;
    const int base_pt = blockIdx.x * PTS_PER_BLOCK + wv * NPTS_PER_WAVE;

    unsigned short* Hb = &H[wv][0][0];

    // ---------------- embedding (writes layer-0 H) ----------------
    {
        const float TWO_PI = 6.28318530717958647692f;
        float b0 = TWO_PI * B[lane];
        float b1 = TWO_PI * B[64 + lane];
        float b2 = TWO_PI * B[128 + lane];
        float bsq = fmaf(b0, b0, b1 * b1);
        #pragma unroll
        for (int b = 0; b < 6; ++b) {
            int pl = b >> 1, mir = b & 1;
            int pt = base_pt + pl; if (pt > npts - 1) pt = npts - 1;
            float x0 = x[2 * pt], x1 = x[2 * pt + 1], tt = t[pt];
            if (mir) x0 = -x0;
            float f = fmaf(x0, b0, fmaf(x1, b1, tt * b2));
            float sf, cf; __sincosf(f, &sf, &cf);
            int rs = (b < 3) ? 5 * b : 16 + 5 * (b - 3);
            Hb[(rs + 0) * 136 + lane] = f2h(sf);
            Hb[(rs + 1) * 136 + lane] = f2h(cf * b2);
            Hb[(rs + 2) * 136 + lane] = f2h(cf * b0);
            Hb[(rs + 3) * 136 + lane] = f2h(cf * b1);
            Hb[(rs + 4) * 136 + lane] = f2h(-sf * bsq);
            Hb[(rs + 0) * 136 + 64 + lane] = f2h(cf);
            Hb[(rs + 1) * 136 + 64 + lane] = f2h(-sf * b2);
            Hb[(rs + 2) * 136 + 64 + lane] = f2h(-sf * b0);
            Hb[(rs + 3) * 136 + 64 + lane] = f2h(-sf * b1);
            Hb[(rs + 4) * 136 + 64 + lane] = f2h(-cf * bsq);
        }
    }
    asm volatile("s_waitcnt lgkmcnt(0)" ::: "memory");

    // ---------------- hidden layers ----------------
    const float vm = (c == 0 || c == 5 || c == 10 || c == 15) ? 1.0f : 0.0f;

    for (int L = 0; L < 4; ++L) {
        // B-fragments: col = own ch-row, k = j (contiguous 8)
        h8 bf[2][4];
        #pragma unroll
        for (int ct = 0; ct < 2; ++ct)
            #pragma unroll
            for (int kt = 0; kt < 4; ++kt)
                bf[ct][kt] = *(const h8*)&Hb[(ct * 16 + c) * 136 + kt * 32 + g * 8];

        const uint4* WL = (const uint4*)Wp + (size_t)L * 2048;   // layer base (uint4)

        #pragma unroll
        for (int jo = 0; jo < 8; ++jo) {
            f4 bv = *(const f4*)&bh[L * 128 + jo * 16 + g * 4];
            f4 a0 = bv * vm, a1 = bv * vm;
            #pragma unroll
            for (int kt = 0; kt < 4; ++kt) {
                union { uint4 u; h8 v; } af;
                af.u = WL[(jo * 4 + kt) * 64 + lane];
                a0 = __builtin_amdgcn_mfma_f32_16x16x32_f16(af.v, bf[0][kt], a0, 0, 0, 0);
                a1 = __builtin_amdgcn_mfma_f32_16x16x32_f16(af.v, bf[1][kt], a1, 0, 0, 0);
            }
            // phase A: raw pre-activations (C layout: row=jo*16+g*4+r, col=c)
            uint2 w0, w1;
            w0.x = pk2h(a0[0], a0[1]); w0.y = pk2h(a0[2], a0[3]);
            w1.x = pk2h(a1[0], a1[1]); w1.y = pk2h(a1[2], a1[3]);
            *(uint2*)&Hb[(0  + c) * 136 + jo * 16 + g * 4] = w0;
            *(uint2*)&Hb[(16 + c) * 136 + jo * 16 + g * 4] = w1;
        }
        asm volatile("s_waitcnt lgkmcnt(0)" ::: "memory");

        // phase B: lane-private j-columns (j = 2*lane, 2*lane+1)
        {
            const int jb = 2 * lane;
            #pragma unroll
            for (int b = 0; b < 6; ++b) {
                int rs = (b < 3) ? 5 * b : 16 + 5 * (b - 3);
                uint32 uv = *(const uint32*)&Hb[(rs + 0) * 136 + jb];
                uint32 ut = *(const uint32*)&Hb[(rs + 1) * 136 + jb];
                uint32 u0 = *(const uint32*)&Hb[(rs + 2) * 136 + jb];
                uint32 u1 = *(const uint32*)&Hb[(rs + 3) * 136 + jb];
                uint32 uL = *(const uint32*)&Hb[(rs + 4) * 136 + jb];
                float v0, v1, t0, t1, p0, p1, q0, q1, L0, L1;
                upk2(uv, v0, v1); upk2(ut, t0, t1); upk2(u0, p0, p1);
                upk2(u1, q0, q1); upk2(uL, L0, L1);
                float y0 = tanh_fast(v0), y1 = tanh_fast(v1);
                float s0 = fmaf(-y0, y0, 1.f), s1 = fmaf(-y1, y1, 1.f);
                float qq0 = fmaf(p0, p0, q0 * q0), qq1 = fmaf(p1, p1, q1 * q1);
                *(uint32*)&Hb[(rs + 0) * 136 + jb] = pk2h(y0, y1);
                *(uint32*)&Hb[(rs + 1) * 136 + jb] = pk2h(s0 * t0, s1 * t1);
                *(uint32*)&Hb[(rs + 2) * 136 + jb] = pk2h(s0 * p0, s1 * p1);
                *(uint32*)&Hb[(rs + 3) * 136 + jb] = pk2h(s0 * q0, s1 * q1);
                *(uint32*)&Hb[(rs + 4) * 136 + jb] =
                    pk2h(s0 * fmaf(-2.f * y0, qq0, L0), s1 * fmaf(-2.f * y1, qq1, L1));
            }
        }
        asm volatile("s_waitcnt lgkmcnt(0)" ::: "memory");
    }

    // ---------------- output layer via MFMA + residual ----------------
    {
        // A = Wout^T (2x128, rows 2..15 zeroed), built in-register
        h8 afo[4];
        const int   mc  = c & 1;
        const float sel = (c < 2) ? 1.0f : 0.0f;
        #pragma unroll
        for (int kt = 0; kt < 4; ++kt) {
            uint32 u[4];
            #pragma unroll
            for (int d = 0; d < 4; ++d) {
                int k = kt * 32 + g * 8 + 2 * d;
                float w0 = Wout[k * 2 + mc] * sel;
                float w1 = Wout[(k + 1) * 2 + mc] * sel;
                u[d] = pk2h(w0, w1);
            }
            afo[kt] = h8_from4(u[0], u[1], u[2], u[3]);
        }
        // B = final H (same fragment pattern as hidden layers)
        h8 bfo[2][4];
        #pragma unroll
        for (int ct = 0; ct < 2; ++ct)
            #pragma unroll
            for (int kt = 0; kt < 4; ++kt)
                bfo[ct][kt] = *(const h8*)&Hb[(ct * 16 + c) * 136 + kt * 32 + g * 8];

        f4 ac0 = {0.f, 0.f, 0.f, 0.f}, ac1 = {0.f, 0.f, 0.f, 0.f};
        #pragma unroll
        for (int kt = 0; kt < 4; ++kt) {
            ac0 = __builtin_amdgcn_mfma_f32_16x16x32_f16(afo[kt], bfo[0][kt], ac0, 0, 0, 0);
            ac1 = __builtin_amdgcn_mfma_f32_16x16x32_f16(afo[kt], bfo[1][kt], ac1, 0, 0, 0);
        }
        // g==0 lanes hold rows 0 (=o0) and 1 (=o1) for col c; stash to LDS
        float* S = (float*)Hb;        // 256 B scratch, H no longer needed
        if (g == 0) {
            f4 pack = {ac0[0], ac0[1], ac1[0], ac1[1]};   // o0ct0,o1ct0,o0ct1,o1ct1
            *(f4*)&S[c * 4] = pack;
        }
        asm volatile("s_waitcnt lgkmcnt(0)" ::: "memory");

        if (lane < 3) {
            int pt = base_pt + lane;
            if (pt < npts) {
                float bo0 = bout[0], bo1 = bout[1];
                float ph = 0.f, cv = 0.f, ptd = 0.f, lp = 0.f;
                #pragma unroll
                for (int br = 0; br < 2; ++br) {
                    int b  = 2 * lane + br;
                    int ct = (b < 3) ? 0 : 1;
                    int cc = ((b < 3) ? b : b - 3) * 5;
                    float o0v = S[(cc + 0) * 4 + 2 * ct] + bo0;
                    float o0t = S[(cc + 1) * 4 + 2 * ct];
                    float o0p = S[(cc + 2) * 4 + 2 * ct];
                    float o0q = S[(cc + 3) * 4 + 2 * ct];
                    float o0L = S[(cc + 4) * 4 + 2 * ct];
                    float o1v = S[(cc + 0) * 4 + 2 * ct + 1] + bo1;
                    float T = tanh_fast(o0v);
                    float p = fmaf(0.5f, T, 0.5f);
                    float s = 0.5f * fmaf(-T, T, 1.f);
                    float lap = s * o0L - 2.f * T * s * fmaf(o0p, o0p, o0q * o0q);
                    float cl = KCOEF * fmaf(0.5f, tanh_fast(o1v), 0.5f);
                    float cb = fmaf(DCOEF, (-2.f * p + 3.f) * p * p, cl);
                    ph  += 0.5f * p;
                    cv  += 0.5f * cb;
                    ptd += 0.5f * s * o0t;
                    lp  += 0.5f * lap;
                }
                float hph = (-2.f * ph + 3.f) * ph * ph;
                float dh  = 6.f * ph * (1.f - ph);
                float dg  = ((4.f * ph - 6.f) * ph + 2.f) * ph;
                float ac  = ptd
                          - 2.f * ((cv - hph * DCOEF - CLE_C) * DCOEF) * dh
                          + dg
                          - 0.01f * lp;
                out[pt] = ac;
            }
        }
    }
}

extern "C" void kernel_launch(void* const* d_in, const int* in_sizes, int n_in,
                              void* d_out, int out_size, void* d_ws, size_t ws_size,
                              hipStream_t stream) {
    const float* x    = (const float*)d_in[0];
    const float* t    = (const float*)d_in[1];
    const float* B    = (const float*)d_in[2];
    const float* Wh   = (const float*)d_in[3];
    const float* bh   = (const float*)d_in[4];
    const float* Wout = (const float*)d_in[5];
    const float* bout = (const float*)d_in[6];
    float* out = (float*)d_out;
    uint32* Wp = (uint32*)d_ws;                       // 128 KB scratch

    const int npts = in_sizes[0] / 2;
    hipLaunchKernelGGL(pinn_prep, dim3(128), dim3(256), 0, stream, Wh, Wp);
    const int nb = (npts + PTS_PER_BLOCK - 1) / PTS_PER_BLOCK;
    hipLaunchKernelGGL(pinn_mfma, dim3(nb), dim3(256), 0, stream,
                       x, t, B, Wp, bh, Wout, bout, out, npts);
}

// Round 5
// 153.953 us; speedup vs baseline: 14.2765x; 1.1623x over previous
//
#include <hip/hip_runtime.h>
#include <math.h>

#define PTS_PER_BLOCK 9
#define NPTS_PER_WAVE 3
#define WAVES_PER_BLOCK 3

typedef _Float16 h8 __attribute__((ext_vector_type(8)));
typedef _Float16 h2 __attribute__((ext_vector_type(2)));
typedef __fp16   fp16x2 __attribute__((ext_vector_type(2)));
typedef float    f4 __attribute__((ext_vector_type(4)));
typedef unsigned int uint32;

// cfg constants
#define CSE_C 0.5f
#define CLE_C 0.00574f
#define DCOEF (CSE_C - CLE_C)          // 0.49426
#define KCOEF (1.0f - CSE_C + CLE_C)   // 0.50574

__device__ __forceinline__ float tanh_fast(float xx) {
    float e = __expf(2.0f * xx);
    float r = __builtin_amdgcn_rcpf(e + 1.0f);
    return fmaf(-2.0f, r, 1.0f);
}
__device__ __forceinline__ unsigned short f2h(float a) {
    union { _Float16 h; unsigned short u; } ua; ua.h = (_Float16)a; return ua.u;
}
__device__ __forceinline__ h2 pkrtz(float a, float b) {
    union { fp16x2 f; h2 h; } x; x.f = __builtin_amdgcn_cvt_pkrtz(a, b); return x.h;
}
__device__ __forceinline__ uint32 pk2h(float a, float b) {
    union { h2 h; uint32 u; } x; x.h = pkrtz(a, b); return x.u;
}
__device__ __forceinline__ h8 h8_from4(uint32 a, uint32 b, uint32 c, uint32 d) {
    union { uint32 u[4]; h8 v; } x; x.u[0] = a; x.u[1] = b; x.u[2] = c; x.u[3] = d;
    return x.v;
}

// ---------------------------------------------------------------------------
// Prep: Wh (4,128,128 f32) -> A-fragment-ordered f16 W^T tiles, [L][jo][kt]
// A-frag (16x16x32 f16): lane holds row m=lane&15, k=(lane>>4)*8+e.
//   Wp[ ((L*8+jo)*4+kt)*256 + lane*4 + d ] packs (k=kt*32+(lane>>4)*8+2d, k+1)
// value = W^T[m,k] = Wh[L][k][jout=jo*16+m]
// ---------------------------------------------------------------------------
extern "C" __global__ __launch_bounds__(256)
void pinn_prep(const float* __restrict__ Wh, uint32* __restrict__ Wp)
{
    int gid  = blockIdx.x * 256 + threadIdx.x;       // 0..32767
    int d    = gid & 3;
    int lane = (gid >> 2) & 63;
    int kt   = (gid >> 8) & 3;
    int jo   = (gid >> 10) & 7;
    int L    = gid >> 13;
    int j    = kt * 32 + (lane >> 4) * 8 + 2 * d;
    int jout = jo * 16 + (lane & 15);
    float w0 = Wh[(L * 128 + j) * 128 + jout];
    float w1 = Wh[(L * 128 + j + 1) * 128 + jout];
    Wp[gid] = pk2h(w0, w1);
}

// ---------------------------------------------------------------------------
// Main: barrier-free. One wave = 3 points = 6 branch-points (bp), 5 channels:
//   ch: 0=value 1=d/dt 2=d/dx0 3=d/dx1 4=laplacian
// Per wave, 32 MFMA columns = 2 col-tiles x (3bp x 5ch + pad).
// H per wave in LDS [32][136] f16; W streamed from global (L2-resident).
// Phase B uses packed v_pk_*_f16 on (j, j+1) pairs.
// ---------------------------------------------------------------------------
extern "C" __global__ __launch_bounds__(192, 4)
void pinn_mfma(const float* __restrict__ x, const float* __restrict__ t,
               const float* __restrict__ B, const uint32* __restrict__ Wp,
               const float* __restrict__ bh, const float* __restrict__ Wout,
               const float* __restrict__ bout, float* __restrict__ out, int npts)
{
    __shared__ __align__(16) unsigned short H[WAVES_PER_BLOCK][32][136]; // 26112 B

    const int tid  = threadIdx.x;
    const int lane = tid & 63;
    const int wv   = tid >> 6;
    const int c    = lane & 15;
    const int g    = lane >> 4;
    const int base_pt = blockIdx.x * PTS_PER_BLOCK + wv * NPTS_PER_WAVE;

    unsigned short* Hb = &H[wv][0][0];

    // ---------------- embedding (writes layer-0 H) ----------------
    {
        const float TWO_PI = 6.28318530717958647692f;
        float b0 = TWO_PI * B[lane];
        float b1 = TWO_PI * B[64 + lane];
        float b2 = TWO_PI * B[128 + lane];
        float bsq = fmaf(b0, b0, b1 * b1);
        #pragma unroll
        for (int b = 0; b < 6; ++b) {
            int pl = b >> 1, mir = b & 1;
            int pt = base_pt + pl; if (pt > npts - 1) pt = npts - 1;
            float x0 = x[2 * pt], x1 = x[2 * pt + 1], tt = t[pt];
            if (mir) x0 = -x0;
            float f = fmaf(x0, b0, fmaf(x1, b1, tt * b2));
            float sf, cf; __sincosf(f, &sf, &cf);
            int rs = (b < 3) ? 5 * b : 16 + 5 * (b - 3);
            Hb[(rs + 0) * 136 + lane] = f2h(sf);
            Hb[(rs + 1) * 136 + lane] = f2h(cf * b2);
            Hb[(rs + 2) * 136 + lane] = f2h(cf * b0);
            Hb[(rs + 3) * 136 + lane] = f2h(cf * b1);
            Hb[(rs + 4) * 136 + lane] = f2h(-sf * bsq);
            Hb[(rs + 0) * 136 + 64 + lane] = f2h(cf);
            Hb[(rs + 1) * 136 + 64 + lane] = f2h(-sf * b2);
            Hb[(rs + 2) * 136 + 64 + lane] = f2h(-sf * b0);
            Hb[(rs + 3) * 136 + 64 + lane] = f2h(-sf * b1);
            Hb[(rs + 4) * 136 + 64 + lane] = f2h(-cf * bsq);
        }
    }
    asm volatile("s_waitcnt lgkmcnt(0)" ::: "memory");

    // ---------------- hidden layers ----------------
    const float vm = (c == 0 || c == 5 || c == 10 || c == 15) ? 1.0f : 0.0f;

    for (int L = 0; L < 4; ++L) {
        // B-fragments: col = own ch-row, k = j (contiguous 8)
        h8 bf[2][4];
        #pragma unroll
        for (int ct = 0; ct < 2; ++ct)
            #pragma unroll
            for (int kt = 0; kt < 4; ++kt)
                bf[ct][kt] = *(const h8*)&Hb[(ct * 16 + c) * 136 + kt * 32 + g * 8];

        const uint4* WL = (const uint4*)Wp + (size_t)L * 2048;   // layer base (uint4)

        #pragma unroll
        for (int jo = 0; jo < 8; ++jo) {
            f4 bv = *(const f4*)&bh[L * 128 + jo * 16 + g * 4];
            f4 a0 = bv * vm, a1 = bv * vm;
            #pragma unroll
            for (int kt = 0; kt < 4; ++kt) {
                union { uint4 u; h8 v; } af;
                af.u = WL[(jo * 4 + kt) * 64 + lane];
                a0 = __builtin_amdgcn_mfma_f32_16x16x32_f16(af.v, bf[0][kt], a0, 0, 0, 0);
                a1 = __builtin_amdgcn_mfma_f32_16x16x32_f16(af.v, bf[1][kt], a1, 0, 0, 0);
            }
            // phase A: raw pre-activations (C layout: row=jo*16+g*4+r, col=c)
            union { h2 h[2]; uint2 u; } w0, w1;
            w0.h[0] = pkrtz(a0[0], a0[1]); w0.h[1] = pkrtz(a0[2], a0[3]);
            w1.h[0] = pkrtz(a1[0], a1[1]); w1.h[1] = pkrtz(a1[2], a1[3]);
            *(uint2*)&Hb[(0  + c) * 136 + jo * 16 + g * 4] = w0.u;
            *(uint2*)&Hb[(16 + c) * 136 + jo * 16 + g * 4] = w1.u;
        }
        asm volatile("s_waitcnt lgkmcnt(0)" ::: "memory");

        // phase B: lane-private j-columns (j = 2*lane, 2*lane+1), packed f16
        {
            const int jb = 2 * lane;
            const h2 m2 = {(_Float16)(-2.0f), (_Float16)(-2.0f)};
            #pragma unroll
            for (int b = 0; b < 6; ++b) {
                int rs = (b < 3) ? 5 * b : 16 + 5 * (b - 3);
                h2 vp = *(const h2*)&Hb[(rs + 0) * 136 + jb];
                h2 tp = *(const h2*)&Hb[(rs + 1) * 136 + jb];
                h2 pp = *(const h2*)&Hb[(rs + 2) * 136 + jb];
                h2 qp = *(const h2*)&Hb[(rs + 3) * 136 + jb];
                h2 Lp = *(const h2*)&Hb[(rs + 4) * 136 + jb];
                float y0 = tanh_fast((float)vp[0]);
                float y1 = tanh_fast((float)vp[1]);
                h2 yp = pkrtz(y0, y1);
                h2 sp = pkrtz(fmaf(-y0, y0, 1.f), fmaf(-y1, y1, 1.f));
                h2 qq = __builtin_elementwise_fma(pp, pp, qp * qp);
                h2 Ln = sp * __builtin_elementwise_fma(yp * m2, qq, Lp);
                *(h2*)&Hb[(rs + 0) * 136 + jb] = yp;
                *(h2*)&Hb[(rs + 1) * 136 + jb] = sp * tp;
                *(h2*)&Hb[(rs + 2) * 136 + jb] = sp * pp;
                *(h2*)&Hb[(rs + 3) * 136 + jb] = sp * qp;
                *(h2*)&Hb[(rs + 4) * 136 + jb] = Ln;
            }
        }
        asm volatile("s_waitcnt lgkmcnt(0)" ::: "memory");
    }

    // ---------------- output layer via MFMA + residual ----------------
    {
        // A = Wout^T (2x128, rows 2..15 zeroed), built in-register
        h8 afo[4];
        const int   mc  = c & 1;
        const float sel = (c < 2) ? 1.0f : 0.0f;
        #pragma unroll
        for (int kt = 0; kt < 4; ++kt) {
            uint32 u[4];
            #pragma unroll
            for (int d = 0; d < 4; ++d) {
                int k = kt * 32 + g * 8 + 2 * d;
                float w0 = Wout[k * 2 + mc] * sel;
                float w1 = Wout[(k + 1) * 2 + mc] * sel;
                u[d] = pk2h(w0, w1);
            }
            afo[kt] = h8_from4(u[0], u[1], u[2], u[3]);
        }
        // B = final H (same fragment pattern as hidden layers)
        h8 bfo[2][4];
        #pragma unroll
        for (int ct = 0; ct < 2; ++ct)
            #pragma unroll
            for (int kt = 0; kt < 4; ++kt)
                bfo[ct][kt] = *(const h8*)&Hb[(ct * 16 + c) * 136 + kt * 32 + g * 8];

        f4 ac0 = {0.f, 0.f, 0.f, 0.f}, ac1 = {0.f, 0.f, 0.f, 0.f};
        #pragma unroll
        for (int kt = 0; kt < 4; ++kt) {
            ac0 = __builtin_amdgcn_mfma_f32_16x16x32_f16(afo[kt], bfo[0][kt], ac0, 0, 0, 0);
            ac1 = __builtin_amdgcn_mfma_f32_16x16x32_f16(afo[kt], bfo[1][kt], ac1, 0, 0, 0);
        }
        // g==0 lanes hold rows 0 (=o0) and 1 (=o1) for col c; stash to LDS
        float* S = (float*)Hb;        // 256 B scratch, H no longer needed
        if (g == 0) {
            f4 pack = {ac0[0], ac0[1], ac1[0], ac1[1]};   // o0ct0,o1ct0,o0ct1,o1ct1
            *(f4*)&S[c * 4] = pack;
        }
        asm volatile("s_waitcnt lgkmcnt(0)" ::: "memory");

        if (lane < 3) {
            int pt = base_pt + lane;
            if (pt < npts) {
                float bo0 = bout[0], bo1 = bout[1];
                float ph = 0.f, cv = 0.f, ptd = 0.f, lp = 0.f;
                #pragma unroll
                for (int br = 0; br < 2; ++br) {
                    int b  = 2 * lane + br;
                    int ct = (b < 3) ? 0 : 1;
                    int cc = ((b < 3) ? b : b - 3) * 5;
                    float o0v = S[(cc + 0) * 4 + 2 * ct] + bo0;
                    float o0t = S[(cc + 1) * 4 + 2 * ct];
                    float o0p = S[(cc + 2) * 4 + 2 * ct];
                    float o0q = S[(cc + 3) * 4 + 2 * ct];
                    float o0L = S[(cc + 4) * 4 + 2 * ct];
                    float o1v = S[(cc + 0) * 4 + 2 * ct + 1] + bo1;
                    float T = tanh_fast(o0v);
                    float p = fmaf(0.5f, T, 0.5f);
                    float s = 0.5f * fmaf(-T, T, 1.f);
                    float lap = s * o0L - 2.f * T * s * fmaf(o0p, o0p, o0q * o0q);
                    float cl = KCOEF * fmaf(0.5f, tanh_fast(o1v), 0.5f);
                    float cb = fmaf(DCOEF, (-2.f * p + 3.f) * p * p, cl);
                    ph  += 0.5f * p;
                    cv  += 0.5f * cb;
                    ptd += 0.5f * s * o0t;
                    lp  += 0.5f * lap;
                }
                float hph = (-2.f * ph + 3.f) * ph * ph;
                float dh  = 6.f * ph * (1.f - ph);
                float dg  = ((4.f * ph - 6.f) * ph + 2.f) * ph;
                float ac  = ptd
                          - 2.f * ((cv - hph * DCOEF - CLE_C) * DCOEF) * dh
                          + dg
                          - 0.01f * lp;
                out[pt] = ac;
            }
        }
    }
}

extern "C" void kernel_launch(void* const* d_in, const int* in_sizes, int n_in,
                              void* d_out, int out_size, void* d_ws, size_t ws_size,
                              hipStream_t stream) {
    const float* x    = (const float*)d_in[0];
    const float* t    = (const float*)d_in[1];
    const float* B    = (const float*)d_in[2];
    const float* Wh   = (const float*)d_in[3];
    const float* bh   = (const float*)d_in[4];
    const float* Wout = (const float*)d_in[5];
    const float* bout = (const float*)d_in[6];
    float* out = (float*)d_out;
    uint32* Wp = (uint32*)d_ws;                       // 128 KB scratch

    const int npts = in_sizes[0] / 2;
    hipLaunchKernelGGL(pinn_prep, dim3(128), dim3(256), 0, stream, Wh, Wp);
    const int nb = (npts + PTS_PER_BLOCK - 1) / PTS_PER_BLOCK;
    hipLaunchKernelGGL(pinn_mfma, dim3(nb), dim3(192), 0, stream,
                       x, t, B, Wp, bh, Wout, bout, out, npts);
}

// Round 6
// 137.485 us; speedup vs baseline: 15.9865x; 1.1198x over previous
//
#include <hip/hip_runtime.h>
#include <math.h>

#define PTS_PER_BLOCK 9
#define NPTS_PER_WAVE 3
#define WAVES_PER_BLOCK 3

typedef _Float16 h8 __attribute__((ext_vector_type(8)));
typedef _Float16 h2 __attribute__((ext_vector_type(2)));
typedef __fp16   fp16x2 __attribute__((ext_vector_type(2)));
typedef float    f4 __attribute__((ext_vector_type(4)));
typedef unsigned int uint32;

// cfg constants
#define CSE_C 0.5f
#define CLE_C 0.00574f
#define DCOEF (CSE_C - CLE_C)          // 0.49426
#define KCOEF (1.0f - CSE_C + CLE_C)   // 0.50574

__device__ __forceinline__ float tanh_fast(float xx) {
    float e = __expf(2.0f * xx);
    float r = __builtin_amdgcn_rcpf(e + 1.0f);
    return fmaf(-2.0f, r, 1.0f);
}
__device__ __forceinline__ unsigned short f2h(float a) {
    union { _Float16 h; unsigned short u; } ua; ua.h = (_Float16)a; return ua.u;
}
__device__ __forceinline__ h2 pkrtz(float a, float b) {
    union { fp16x2 f; h2 h; } x; x.f = __builtin_amdgcn_cvt_pkrtz(a, b); return x.h;
}
__device__ __forceinline__ uint32 pk2h(float a, float b) {
    union { h2 h; uint32 u; } x; x.h = pkrtz(a, b); return x.u;
}
__device__ __forceinline__ h8 h8_from4(uint32 a, uint32 b, uint32 c, uint32 d) {
    union { uint32 u[4]; h8 v; } x; x.u[0] = a; x.u[1] = b; x.u[2] = c; x.u[3] = d;
    return x.v;
}

// ---------------------------------------------------------------------------
// Prep: Wh (4,128,128 f32) -> A-fragment-ordered f16 W^T tiles, [L][jo][kt]
// A-frag (16x16x32 f16): lane holds row m=lane&15, k=(lane>>4)*8+e.
//   Wp[ ((L*8+jo)*4+kt)*256 + lane*4 + d ] packs (k=kt*32+(lane>>4)*8+2d, k+1)
// value = W^T[m,k] = Wh[L][k][jout=jo*16+m]
// ---------------------------------------------------------------------------
extern "C" __global__ __launch_bounds__(256)
void pinn_prep(const float* __restrict__ Wh, uint32* __restrict__ Wp)
{
    int gid  = blockIdx.x * 256 + threadIdx.x;       // 0..32767
    int d    = gid & 3;
    int lane = (gid >> 2) & 63;
    int kt   = (gid >> 8) & 3;
    int jo   = (gid >> 10) & 7;
    int L    = gid >> 13;
    int j    = kt * 32 + (lane >> 4) * 8 + 2 * d;
    int jout = jo * 16 + (lane & 15);
    float w0 = Wh[(L * 128 + j) * 128 + jout];
    float w1 = Wh[(L * 128 + j + 1) * 128 + jout];
    Wp[gid] = pk2h(w0, w1);
}

// ---------------------------------------------------------------------------
// Main: barrier-free. One wave = 3 points = 6 branch-points (bp), 5 channels:
//   ch: 0=value 1=d/dt 2=d/dx0 3=d/dx1 4=laplacian
// Per wave, 32 MFMA columns = 2 col-tiles x (3bp x 5ch + pad).
// H per wave in LDS [32][136] f16; W streamed from global (L2-resident),
// double-buffered 2 jo-tiles deep. Bias applied in phase B (packed f16).
// ---------------------------------------------------------------------------
extern "C" __global__ __launch_bounds__(192, 4)
void pinn_mfma(const float* __restrict__ x, const float* __restrict__ t,
               const float* __restrict__ B, const uint32* __restrict__ Wp,
               const float* __restrict__ bh, const float* __restrict__ Wout,
               const float* __restrict__ bout, float* __restrict__ out, int npts)
{
    __shared__ __align__(16) unsigned short H[WAVES_PER_BLOCK][32][136]; // 26112 B

    const int tid  = threadIdx.x;
    const int lane = tid & 63;
    const int wv   = tid >> 6;
    const int c    = lane & 15;
    const int g    = lane >> 4;
    const int base_pt = blockIdx.x * PTS_PER_BLOCK + wv * NPTS_PER_WAVE;

    unsigned short* Hb = &H[wv][0][0];

    // ---------------- embedding (writes layer-0 H) ----------------
    {
        const float TWO_PI = 6.28318530717958647692f;
        float b0 = TWO_PI * B[lane];
        float b1 = TWO_PI * B[64 + lane];
        float b2 = TWO_PI * B[128 + lane];
        float bsq = fmaf(b0, b0, b1 * b1);
        #pragma unroll
        for (int b = 0; b < 6; ++b) {
            int pl = b >> 1, mir = b & 1;
            int pt = base_pt + pl; if (pt > npts - 1) pt = npts - 1;
            float x0 = x[2 * pt], x1 = x[2 * pt + 1], tt = t[pt];
            if (mir) x0 = -x0;
            float f = fmaf(x0, b0, fmaf(x1, b1, tt * b2));
            float sf, cf; __sincosf(f, &sf, &cf);
            int rs = (b < 3) ? 5 * b : 16 + 5 * (b - 3);
            Hb[(rs + 0) * 136 + lane] = f2h(sf);
            Hb[(rs + 1) * 136 + lane] = f2h(cf * b2);
            Hb[(rs + 2) * 136 + lane] = f2h(cf * b0);
            Hb[(rs + 3) * 136 + lane] = f2h(cf * b1);
            Hb[(rs + 4) * 136 + lane] = f2h(-sf * bsq);
            Hb[(rs + 0) * 136 + 64 + lane] = f2h(cf);
            Hb[(rs + 1) * 136 + 64 + lane] = f2h(-sf * b2);
            Hb[(rs + 2) * 136 + 64 + lane] = f2h(-sf * b0);
            Hb[(rs + 3) * 136 + 64 + lane] = f2h(-sf * b1);
            Hb[(rs + 4) * 136 + 64 + lane] = f2h(-cf * bsq);
        }
    }
    asm volatile("s_waitcnt lgkmcnt(0)" ::: "memory");

    // ---------------- hidden layers ----------------
    for (int L = 0; L < 4; ++L) {
        // B-fragments: col = own ch-row, k = j (contiguous 8)
        h8 bf[2][4];
        #pragma unroll
        for (int ct = 0; ct < 2; ++ct)
            #pragma unroll
            for (int kt = 0; kt < 4; ++kt)
                bf[ct][kt] = *(const h8*)&Hb[(ct * 16 + c) * 136 + kt * 32 + g * 8];

        const uint4* WL = (const uint4*)Wp + (size_t)L * 2048;   // layer base (uint4)

        // W tiles double-buffered 2 jo-steps deep (static idx under unroll)
        uint4 wt[2][4];
        #pragma unroll
        for (int kt = 0; kt < 4; ++kt) wt[0][kt] = WL[kt * 64 + lane];

        #pragma unroll
        for (int jo = 0; jo < 8; ++jo) {
            const int cur = jo & 1, nxt = cur ^ 1;
            if (jo < 7) {
                #pragma unroll
                for (int kt = 0; kt < 4; ++kt)
                    wt[nxt][kt] = WL[((jo + 1) * 4 + kt) * 64 + lane];
            }
            f4 a0 = {0.f, 0.f, 0.f, 0.f}, a1 = {0.f, 0.f, 0.f, 0.f};
            #pragma unroll
            for (int kt = 0; kt < 4; ++kt) {
                union { uint4 u; h8 v; } af;
                af.u = wt[cur][kt];
                a0 = __builtin_amdgcn_mfma_f32_16x16x32_f16(af.v, bf[0][kt], a0, 0, 0, 0);
                a1 = __builtin_amdgcn_mfma_f32_16x16x32_f16(af.v, bf[1][kt], a1, 0, 0, 0);
            }
            // phase A: raw pre-activations (C layout: row=jo*16+g*4+r, col=c)
            union { h2 h[2]; uint2 u; } w0, w1;
            w0.h[0] = pkrtz(a0[0], a0[1]); w0.h[1] = pkrtz(a0[2], a0[3]);
            w1.h[0] = pkrtz(a1[0], a1[1]); w1.h[1] = pkrtz(a1[2], a1[3]);
            *(uint2*)&Hb[(0  + c) * 136 + jo * 16 + g * 4] = w0.u;
            *(uint2*)&Hb[(16 + c) * 136 + jo * 16 + g * 4] = w1.u;
        }
        asm volatile("s_waitcnt lgkmcnt(0)" ::: "memory");

        // phase B: lane-private j-columns (j = 2*lane, 2*lane+1), packed f16.
        // Bias (value channel only) applied here.
        {
            const int jb = 2 * lane;
            const float2 bj = *(const float2*)&bh[L * 128 + jb];
            const h2 bias2 = pkrtz(bj.x, bj.y);
            const h2 m2 = {(_Float16)(-2.0f), (_Float16)(-2.0f)};
            #pragma unroll
            for (int b = 0; b < 6; ++b) {
                int rs = (b < 3) ? 5 * b : 16 + 5 * (b - 3);
                h2 vp = *(const h2*)&Hb[(rs + 0) * 136 + jb];
                h2 tp = *(const h2*)&Hb[(rs + 1) * 136 + jb];
                h2 pp = *(const h2*)&Hb[(rs + 2) * 136 + jb];
                h2 qp = *(const h2*)&Hb[(rs + 3) * 136 + jb];
                h2 Lp = *(const h2*)&Hb[(rs + 4) * 136 + jb];
                vp = vp + bias2;
                float y0 = tanh_fast((float)vp[0]);
                float y1 = tanh_fast((float)vp[1]);
                h2 yp = pkrtz(y0, y1);
                h2 sp = pkrtz(fmaf(-y0, y0, 1.f), fmaf(-y1, y1, 1.f));
                h2 qq = __builtin_elementwise_fma(pp, pp, qp * qp);
                h2 Ln = sp * __builtin_elementwise_fma(yp * m2, qq, Lp);
                *(h2*)&Hb[(rs + 0) * 136 + jb] = yp;
                *(h2*)&Hb[(rs + 1) * 136 + jb] = sp * tp;
                *(h2*)&Hb[(rs + 2) * 136 + jb] = sp * pp;
                *(h2*)&Hb[(rs + 3) * 136 + jb] = sp * qp;
                *(h2*)&Hb[(rs + 4) * 136 + jb] = Ln;
            }
        }
        asm volatile("s_waitcnt lgkmcnt(0)" ::: "memory");
    }

    // ---------------- output layer via MFMA + residual ----------------
    {
        // A = Wout^T (2x128, rows 2..15 zeroed), built in-register
        h8 afo[4];
        const int   mc  = c & 1;
        const float sel = (c < 2) ? 1.0f : 0.0f;
        #pragma unroll
        for (int kt = 0; kt < 4; ++kt) {
            uint32 u[4];
            #pragma unroll
            for (int d = 0; d < 4; ++d) {
                int k = kt * 32 + g * 8 + 2 * d;
                float w0 = Wout[k * 2 + mc] * sel;
                float w1 = Wout[(k + 1) * 2 + mc] * sel;
                u[d] = pk2h(w0, w1);
            }
            afo[kt] = h8_from4(u[0], u[1], u[2], u[3]);
        }
        // B = final H (same fragment pattern as hidden layers)
        h8 bfo[2][4];
        #pragma unroll
        for (int ct = 0; ct < 2; ++ct)
            #pragma unroll
            for (int kt = 0; kt < 4; ++kt)
                bfo[ct][kt] = *(const h8*)&Hb[(ct * 16 + c) * 136 + kt * 32 + g * 8];

        f4 ac0 = {0.f, 0.f, 0.f, 0.f}, ac1 = {0.f, 0.f, 0.f, 0.f};
        #pragma unroll
        for (int kt = 0; kt < 4; ++kt) {
            ac0 = __builtin_amdgcn_mfma_f32_16x16x32_f16(afo[kt], bfo[0][kt], ac0, 0, 0, 0);
            ac1 = __builtin_amdgcn_mfma_f32_16x16x32_f16(afo[kt], bfo[1][kt], ac1, 0, 0, 0);
        }
        // g==0 lanes hold rows 0 (=o0) and 1 (=o1) for col c; stash to LDS
        float* S = (float*)Hb;        // 256 B scratch, H no longer needed
        if (g == 0) {
            f4 pack = {ac0[0], ac0[1], ac1[0], ac1[1]};   // o0ct0,o1ct0,o0ct1,o1ct1
            *(f4*)&S[c * 4] = pack;
        }
        asm volatile("s_waitcnt lgkmcnt(0)" ::: "memory");

        if (lane < 3) {
            int pt = base_pt + lane;
            if (pt < npts) {
                float bo0 = bout[0], bo1 = bout[1];
                float ph = 0.f, cv = 0.f, ptd = 0.f, lp = 0.f;
                #pragma unroll
                for (int br = 0; br < 2; ++br) {
                    int b  = 2 * lane + br;
                    int ct = (b < 3) ? 0 : 1;
                    int cc = ((b < 3) ? b : b - 3) * 5;
                    float o0v = S[(cc + 0) * 4 + 2 * ct] + bo0;
                    float o0t = S[(cc + 1) * 4 + 2 * ct];
                    float o0p = S[(cc + 2) * 4 + 2 * ct];
                    float o0q = S[(cc + 3) * 4 + 2 * ct];
                    float o0L = S[(cc + 4) * 4 + 2 * ct];
                    float o1v = S[(cc + 0) * 4 + 2 * ct + 1] + bo1;
                    float T = tanh_fast(o0v);
                    float p = fmaf(0.5f, T, 0.5f);
                    float s = 0.5f * fmaf(-T, T, 1.f);
                    float lap = s * o0L - 2.f * T * s * fmaf(o0p, o0p, o0q * o0q);
                    float cl = KCOEF * fmaf(0.5f, tanh_fast(o1v), 0.5f);
                    float cb = fmaf(DCOEF, (-2.f * p + 3.f) * p * p, cl);
                    ph  += 0.5f * p;
                    cv  += 0.5f * cb;
                    ptd += 0.5f * s * o0t;
                    lp  += 0.5f * lap;
                }
                float hph = (-2.f * ph + 3.f) * ph * ph;
                float dh  = 6.f * ph * (1.f - ph);
                float dg  = ((4.f * ph - 6.f) * ph + 2.f) * ph;
                float ac  = ptd
                          - 2.f * ((cv - hph * DCOEF - CLE_C) * DCOEF) * dh
                          + dg
                          - 0.01f * lp;
                out[pt] = ac;
            }
        }
    }
}

extern "C" void kernel_launch(void* const* d_in, const int* in_sizes, int n_in,
                              void* d_out, int out_size, void* d_ws, size_t ws_size,
                              hipStream_t stream) {
    const float* x    = (const float*)d_in[0];
    const float* t    = (const float*)d_in[1];
    const float* B    = (const float*)d_in[2];
    const float* Wh   = (const float*)d_in[3];
    const float* bh   = (const float*)d_in[4];
    const float* Wout = (const float*)d_in[5];
    const float* bout = (const float*)d_in[6];
    float* out = (float*)d_out;
    uint32* Wp = (uint32*)d_ws;                       // 128 KB scratch

    const int npts = in_sizes[0] / 2;
    hipLaunchKernelGGL(pinn_prep, dim3(128), dim3(256), 0, stream, Wh, Wp);
    const int nb = (npts + PTS_PER_BLOCK - 1) / PTS_PER_BLOCK;
    hipLaunchKernelGGL(pinn_mfma, dim3(nb), dim3(192), 0, stream,
                       x, t, B, Wp, bh, Wout, bout, out, npts);
}